// Round 4
// baseline (429.536 us; speedup 1.0000x reference)
//
#include <hip/hip_runtime.h>
#include <cmath>

typedef __attribute__((ext_vector_type(8))) short bf16x8;
typedef __attribute__((ext_vector_type(4))) short bf16x4;
typedef __attribute__((ext_vector_type(4))) float f32x4;

constexpr int B_ = 4;
constexpr int S_ = 4096;
constexpr int DM_ = 1024;
constexpr int DK_ = 64;
constexpr int NROW = B_ * S_;   // 16384

__device__ __forceinline__ short f2bf(float x) {
  union { float f; unsigned u; } c; c.f = x;
  unsigned r = (c.u + 0x7FFF + ((c.u >> 16) & 1)) >> 16;  // RNE
  return (short)r;
}
__device__ __forceinline__ float bf2f(short h) {
  union { float f; unsigned u; } c; c.u = ((unsigned)(unsigned short)h) << 16;
  return c.f;
}

// ---------------------------------------------------------------------------
// Kernel 1: projections (z=0..2) + mask packing (z=3) in ONE dispatch so the
// mask's 67 MB of HBM reads overlap proj's latency-bound staging.
// proj: tile 64 rows x 64 cols, BK=64; X converted to bf16 hi/lo AT STAGING
// so the inner loop is pure ds_read_b128 + MFMA.
// qh/kh bf16 row-major; V transposed vhT[b][d][s].
// ---------------------------------------------------------------------------
__global__ __launch_bounds__(256) void proj_mfma(
    const float* __restrict__ q, const float* __restrict__ k,
    const float* __restrict__ v,
    const float* __restrict__ Wq, const float* __restrict__ bq,
    const float* __restrict__ Wk, const float* __restrict__ bk,
    const float* __restrict__ Wv, const float* __restrict__ bv,
    short* __restrict__ qh, short* __restrict__ kh, short* __restrict__ vhT,
    const int* __restrict__ mask, unsigned long long* __restrict__ mbits) {
  const int mat = blockIdx.z;
  const int t = threadIdx.x;
  const int lane = t & 63, w = t >> 6;

  if (mat == 3) {  // ---- mask packing: 256 blocks x 4 waves = 1024 wave-rows
    const int wid = blockIdx.x * 4 + w;   // 0..1023
#pragma unroll
    for (int j = 0; j < 4; ++j) {
      const int row = wid + j * 1024;
      const size_t base = (size_t)row * S_;
      for (int it = 0; it < 64; ++it) {
        int m = mask[base + it * 64 + lane];
        unsigned long long b = __ballot(m != 0);
        if (lane == 0) mbits[(size_t)row * 64 + it] = b;
      }
    }
    return;
  }

  const float* X    = mat == 0 ? q  : (mat == 1 ? k  : v);
  const float* W    = mat == 0 ? Wq : (mat == 1 ? Wk : Wv);
  const float* bias = mat == 0 ? bq : (mat == 1 ? bk : bv);

  __shared__ short Xh[64][72];   // 9.2 KB each
  __shared__ short Xl[64][72];
  __shared__ short Ws[64][72];

  const int row0 = blockIdx.x * 64;
  const int quad = lane >> 4, l16 = lane & 15;

  f32x4 acc[4] = {};

  for (int k0 = 0; k0 < DM_; k0 += 64) {
    __syncthreads();
    {  // stage X 64x64 fp32 -> bf16 hi/lo planes
      const int r = t >> 2, cq = (t & 3) * 16;
      const float* src = X + (size_t)(row0 + r) * DM_ + k0 + cq;
      f32x4 a0 = *(const f32x4*)src, a1 = *(const f32x4*)(src + 4);
      f32x4 a2 = *(const f32x4*)(src + 8), a3 = *(const f32x4*)(src + 12);
      bf16x8 h0, h1, l0, l1;
#pragma unroll
      for (int j = 0; j < 4; ++j) {
        short h;
        h = f2bf(a0[j]); h0[j] = h;     l0[j]     = f2bf(a0[j] - bf2f(h));
        h = f2bf(a1[j]); h0[j + 4] = h; l0[j + 4] = f2bf(a1[j] - bf2f(h));
        h = f2bf(a2[j]); h1[j] = h;     l1[j]     = f2bf(a2[j] - bf2f(h));
        h = f2bf(a3[j]); h1[j + 4] = h; l1[j + 4] = f2bf(a3[j] - bf2f(h));
      }
      *(bf16x8*)&Xh[r][cq] = h0; *(bf16x8*)&Xh[r][cq + 8] = h1;
      *(bf16x8*)&Xl[r][cq] = l0; *(bf16x8*)&Xl[r][cq + 8] = l1;
    }
    {  // stage W 64x64 -> bf16
      const int c = t >> 2, kk = (t & 3) * 16;
      const float* src = W + (size_t)c * DM_ + k0 + kk;
      f32x4 a0 = *(const f32x4*)src, a1 = *(const f32x4*)(src + 4);
      f32x4 a2 = *(const f32x4*)(src + 8), a3 = *(const f32x4*)(src + 12);
      bf16x8 w0, w1;
#pragma unroll
      for (int j = 0; j < 4; ++j) {
        w0[j] = f2bf(a0[j]); w0[j + 4] = f2bf(a1[j]);
        w1[j] = f2bf(a2[j]); w1[j + 4] = f2bf(a3[j]);
      }
      *(bf16x8*)&Ws[c][kk]     = w0;
      *(bf16x8*)&Ws[c][kk + 8] = w1;
    }
    __syncthreads();

#pragma unroll
    for (int c = 0; c < 2; ++c) {
      bf16x8 ahi = *(const bf16x8*)&Xh[16 * w + l16][c * 32 + quad * 8];
      bf16x8 alo = *(const bf16x8*)&Xl[16 * w + l16][c * 32 + quad * 8];
#pragma unroll
      for (int ct = 0; ct < 4; ++ct) {
        bf16x8 bw = *(const bf16x8*)&Ws[16 * ct + l16][c * 32 + quad * 8];
        acc[ct] = __builtin_amdgcn_mfma_f32_16x16x32_bf16(ahi, bw, acc[ct], 0, 0, 0);
        acc[ct] = __builtin_amdgcn_mfma_f32_16x16x32_bf16(alo, bw, acc[ct], 0, 0, 0);
      }
    }
  }

  short* dstq = (mat == 0) ? qh : kh;
#pragma unroll
  for (int ct = 0; ct < 4; ++ct) {
    const float bs = bias[16 * ct + l16];
#pragma unroll
    for (int reg = 0; reg < 4; ++reg) {
      int r = row0 + 16 * w + quad * 4 + reg;
      int c = 16 * ct + l16;
      short hv = f2bf(acc[ct][reg] + bs);
      if (mat == 2)
        vhT[((size_t)(r >> 12) * DK_ + c) * S_ + (r & 4095)] = hv;
      else
        dstq[(size_t)r * DK_ + c] = hv;
    }
  }
}

// ---------------------------------------------------------------------------
// Kernel 2: split-K flash attention, bf16 MFMA, transposed formulation.
// blockIdx = (q-tile, split, batch).  Each split covers S_/ns keys, writes
// UNNORMALIZED O^T partials + per-row (m, l).
// ---------------------------------------------------------------------------
__global__ __launch_bounds__(256) void attn_mfma(
    const short* __restrict__ qh, const short* __restrict__ kh,
    const short* __restrict__ vhT, const unsigned int* __restrict__ mbits,
    float* __restrict__ Opart, float* __restrict__ mpart,
    float* __restrict__ lpart, int ns) {
  __shared__ short ks[64][72];
  __shared__ short vt[64][72];
  __shared__ short ps[4][16][72];

  const int b = blockIdx.z;
  const int split = blockIdx.y;
  const int q0 = blockIdx.x * 64;
  const int t = threadIdx.x, lane = t & 63, w = t >> 6;
  const int quad = lane >> 4, l16 = lane & 15;
  const int myq = q0 + 16 * w + l16;

  const int kt0 = split * (S_ / ns);
  const int kt1 = kt0 + S_ / ns;

  bf16x8 qf[2];
  {
    const short* src = qh + ((size_t)b * S_ + myq) * DK_ + quad * 8;
    qf[0] = *(const bf16x8*)src;
    qf[1] = *(const bf16x8*)(src + 32);
  }

  f32x4 ao[4] = {};
  float m_i = -INFINITY, l_i = 0.0f;

  const int sr = t >> 2;        // staging row 0..63
  const int sseg = t & 3;       // 16B segments sseg, sseg+4

  for (int kt = kt0; kt < kt1; kt += 64) {
    __syncthreads();
    {
      const short* srck = kh + ((size_t)b * S_ + kt + sr) * DK_;
      *(bf16x8*)&ks[sr][8 * sseg]       = *(const bf16x8*)(srck + 8 * sseg);
      *(bf16x8*)&ks[sr][8 * (sseg + 4)] = *(const bf16x8*)(srck + 8 * (sseg + 4));
      const short* srcv = vhT + ((size_t)b * DK_ + sr) * S_ + kt;
      *(bf16x8*)&vt[sr][8 * sseg]       = *(const bf16x8*)(srcv + 8 * sseg);
      *(bf16x8*)&vt[sr][8 * (sseg + 4)] = *(const bf16x8*)(srcv + 8 * (sseg + 4));
    }
    const uint2 mw = *(const uint2*)&mbits[(size_t)myq * 128 + (kt >> 5)];
    __syncthreads();

    // S^T = K . Q^T
    f32x4 sacc[4] = {};
#pragma unroll
    for (int c = 0; c < 2; ++c)
#pragma unroll
      for (int tt = 0; tt < 4; ++tt) {
        bf16x8 a = *(const bf16x8*)&ks[16 * tt + l16][c * 32 + quad * 8];
        sacc[tt] = __builtin_amdgcn_mfma_f32_16x16x32_bf16(a, qf[c], sacc[tt], 0, 0, 0);
      }

    // mask + scale
    float sc[16];
#pragma unroll
    for (int tt = 0; tt < 4; ++tt) {
      unsigned wrd = (tt & 2) ? mw.y : mw.x;
      int base = (tt & 1) * 16 + quad * 4;
#pragma unroll
      for (int r = 0; r < 4; ++r)
        sc[tt * 4 + r] = ((wrd >> (base + r)) & 1) ? sacc[tt][r] * 0.125f : -1e9f;
    }

    // per-lane online softmax (lane owns one q-col)
    float mx = sc[0];
#pragma unroll
    for (int i = 1; i < 16; ++i) mx = fmaxf(mx, sc[i]);
    mx = fmaxf(mx, __shfl_xor(mx, 16));
    mx = fmaxf(mx, __shfl_xor(mx, 32));
    float m_new = fmaxf(m_i, mx);
    float alpha = __expf(m_i - m_new);   // first iter: exp(-inf)=0
    float p[16], sum = 0.0f;
#pragma unroll
    for (int i = 0; i < 16; ++i) { p[i] = __expf(sc[i] - m_new); sum += p[i]; }
    sum += __shfl_xor(sum, 16);
    sum += __shfl_xor(sum, 32);
    l_i = l_i * alpha + sum;
    m_i = m_new;

    // P^T -> LDS bf16
#pragma unroll
    for (int tt = 0; tt < 4; ++tt) {
      bf16x4 pk;
#pragma unroll
      for (int r = 0; r < 4; ++r) pk[r] = f2bf(p[tt * 4 + r]);
      *(bf16x4*)&ps[w][l16][16 * tt + quad * 4] = pk;
    }

#pragma unroll
    for (int dt = 0; dt < 4; ++dt)
#pragma unroll
      for (int r = 0; r < 4; ++r) ao[dt][r] *= alpha;

    // O^T += V^T . P^T
#pragma unroll
    for (int c = 0; c < 2; ++c) {
      bf16x8 bp = *(const bf16x8*)&ps[w][l16][c * 32 + quad * 8];
#pragma unroll
      for (int dt = 0; dt < 4; ++dt) {
        bf16x8 av = *(const bf16x8*)&vt[16 * dt + l16][c * 32 + quad * 8];
        ao[dt] = __builtin_amdgcn_mfma_f32_16x16x32_bf16(av, bp, ao[dt], 0, 0, 0);
      }
    }
  }

  const size_t prow = (size_t)split * NROW + (size_t)b * S_ + myq;
#pragma unroll
  for (int dt = 0; dt < 4; ++dt)
    *(f32x4*)&Opart[prow * DK_ + 16 * dt + quad * 4] = ao[dt];
  if (quad == 0) {
    mpart[prow] = m_i;
    lpart[prow] = l_i;
  }
}

// ---------------------------------------------------------------------------
// Kernel 2b: combine split partials -> o bf16.
// ---------------------------------------------------------------------------
__global__ __launch_bounds__(256) void attn_combine(
    const float* __restrict__ Opart, const float* __restrict__ mpart,
    const float* __restrict__ lpart, short* __restrict__ o_bf, int ns) {
  const int t = threadIdx.x;
  const int row = blockIdx.x * 64 + (t >> 2);
  const int c0 = (t & 3) * 16;

  float M = -INFINITY;
  for (int s = 0; s < ns; ++s) M = fmaxf(M, mpart[(size_t)s * NROW + row]);
  float L = 0.0f, wt[8];
  for (int s = 0; s < ns; ++s) {
    wt[s] = __expf(mpart[(size_t)s * NROW + row] - M);
    L += wt[s] * lpart[(size_t)s * NROW + row];
  }
  float acc[16] = {};
  for (int s = 0; s < ns; ++s) {
    const float* src = Opart + ((size_t)s * NROW + row) * DK_ + c0;
#pragma unroll
    for (int j = 0; j < 16; j += 4) {
      f32x4 vv = *(const f32x4*)(src + j);
#pragma unroll
      for (int r = 0; r < 4; ++r) acc[j + r] += wt[s] * vv[r];
    }
  }
  const float inv = 1.0f / L;
  bf16x8 o0, o1;
#pragma unroll
  for (int j = 0; j < 8; ++j) {
    o0[j] = f2bf(acc[j] * inv);
    o1[j] = f2bf(acc[j + 8] * inv);
  }
  *(bf16x8*)&o_bf[(size_t)row * DK_ + c0]     = o0;
  *(bf16x8*)&o_bf[(size_t)row * DK_ + c0 + 8] = o1;
}

// ---------------------------------------------------------------------------
// Kernel 3: output projection, bf16 MFMA.  Tile 64 s x 256 dm, K=64.
// ---------------------------------------------------------------------------
__global__ __launch_bounds__(256) void outproj_mfma(
    const short* __restrict__ o_bf, const float* __restrict__ Wo,
    const float* __restrict__ bo, float* __restrict__ out) {
  __shared__ short os[64][72];
  __shared__ short wos[256][72];

  const int t = threadIdx.x, lane = t & 63, w = t >> 6;
  const int quad = lane >> 4, l16 = lane & 15;
  const int s0 = blockIdx.y * 64;
  const int dm0 = blockIdx.x * 256;

  {  // stage o (bf16 copy)
    int r = t >> 2, cq = (t & 3) * 16;
    const short* src = o_bf + (size_t)(s0 + r) * DK_ + cq;
    *(bf16x8*)&os[r][cq]     = *(const bf16x8*)src;
    *(bf16x8*)&os[r][cq + 8] = *(const bf16x8*)(src + 8);
  }
#pragma unroll
  for (int pass = 0; pass < 4; ++pass) {  // stage Wo tile 256x64 fp32->bf16
    int r = pass * 64 + (t >> 2), cq = (t & 3) * 16;
    const float* src = Wo + (size_t)(dm0 + r) * DK_ + cq;
    f32x4 a0 = *(const f32x4*)src, a1 = *(const f32x4*)(src + 4);
    f32x4 a2 = *(const f32x4*)(src + 8), a3 = *(const f32x4*)(src + 12);
    bf16x8 v0, v1;
#pragma unroll
    for (int j = 0; j < 4; ++j) {
      v0[j] = f2bf(a0[j]); v0[j + 4] = f2bf(a1[j]);
      v1[j] = f2bf(a2[j]); v1[j + 4] = f2bf(a3[j]);
    }
    *(bf16x8*)&wos[r][cq]     = v0;
    *(bf16x8*)&wos[r][cq + 8] = v1;
  }
  __syncthreads();

  bf16x8 af[2];
#pragma unroll
  for (int c = 0; c < 2; ++c)
    af[c] = *(const bf16x8*)&os[16 * w + l16][c * 32 + quad * 8];

  f32x4 acc[16] = {};
#pragma unroll
  for (int c = 0; c < 2; ++c)
#pragma unroll
    for (int nt = 0; nt < 16; ++nt) {
      bf16x8 bw = *(const bf16x8*)&wos[16 * nt + l16][c * 32 + quad * 8];
      acc[nt] = __builtin_amdgcn_mfma_f32_16x16x32_bf16(af[c], bw, acc[nt], 0, 0, 0);
    }

  float bias_r[16];
#pragma unroll
  for (int nt = 0; nt < 16; ++nt) bias_r[nt] = bo[dm0 + 16 * nt + l16];

#pragma unroll
  for (int nt = 0; nt < 16; ++nt)
#pragma unroll
    for (int reg = 0; reg < 4; ++reg) {
      int s = s0 + 16 * w + quad * 4 + reg;
      int dm = dm0 + 16 * nt + l16;
      out[(size_t)s * DM_ + dm] = acc[nt][reg] + bias_r[nt];
    }
}

// ---------------------------------------------------------------------------
extern "C" void kernel_launch(void* const* d_in, const int* in_sizes, int n_in,
                              void* d_out, int out_size, void* d_ws,
                              size_t ws_size, hipStream_t stream) {
  (void)in_sizes; (void)n_in; (void)out_size;
  const float* q  = (const float*)d_in[0];
  const float* k  = (const float*)d_in[1];
  const float* v  = (const float*)d_in[2];
  const int* mask = (const int*)d_in[3];
  const float* Wq = (const float*)d_in[4];
  const float* bq = (const float*)d_in[5];
  const float* Wk = (const float*)d_in[6];
  const float* bk = (const float*)d_in[7];
  const float* Wv = (const float*)d_in[8];
  const float* bv = (const float*)d_in[9];
  const float* Wo = (const float*)d_in[10];
  const float* bo = (const float*)d_in[11];
  float* out = (float*)d_out;

  // ws layout: qh 2MB | kh 2MB | vhT 2MB | mbits 2MB | o_bf 2MB |
  //            mpart 512KB | lpart 512KB | Opart ns*4MB
  short* qh  = (short*)d_ws;
  short* kh  = qh + (size_t)NROW * DK_;
  short* vhT = kh + (size_t)NROW * DK_;
  unsigned int* mbits = (unsigned int*)(vhT + (size_t)NROW * DK_);
  short* o_bf = (short*)(mbits + (size_t)S_ * 128);
  float* mpart = (float*)(o_bf + (size_t)NROW * DK_);
  float* lpart = mpart + 8 * NROW;           // reserved for ns up to 8
  float* Opart = lpart + 8 * NROW;

  const size_t base_bytes = (size_t)((char*)Opart - (char*)d_ws);
  const size_t per_split = (size_t)NROW * DK_ * sizeof(float);   // 4 MB
  int ns = 1;
  if (ws_size >= base_bytes + 8 * per_split) ns = 8;
  else if (ws_size >= base_bytes + 4 * per_split) ns = 4;
  else if (ws_size >= base_bytes + 2 * per_split) ns = 2;

  proj_mfma<<<dim3(NROW / 64, 1, 4), 256, 0, stream>>>(
      q, k, v, Wq, bq, Wk, bk, Wv, bv, qh, kh, vhT,
      mask, (unsigned long long*)mbits);
  attn_mfma<<<dim3(S_ / 64, ns, B_), 256, 0, stream>>>(
      qh, kh, vhT, mbits, Opart, mpart, lpart, ns);
  attn_combine<<<NROW / 64, 256, 0, stream>>>(Opart, mpart, lpart, o_bf, ns);
  outproj_mfma<<<dim3(DM_ / 256, NROW / 64), 256, 0, stream>>>(o_bf, Wo, bo, out);
}